// Round 12
// baseline (433.771 us; speedup 1.0000x reference)
//
#include <hip/hip_runtime.h>

// VanillaLinearAttention: B=8 N=4096 C=1024 H=16 D=64, M=B*N=32768.
// prep: cast x + transpose W's; QKV = x@[Wq|Wk|Wv] (256^2 4-phase counted-vmcnt
// MFMA GEMM, 32x32x16 frags, fused q-softmax tn<4 + fused exp(k) tn 4..7);
// kv = sum_n expk*v; kv_scale (1/colsum); W2T_b = wot_h @ kvN_h; 
// out = q_sm @ W2_b + bo (batched final GEMM).

typedef unsigned short u16;
typedef __bf16 bf16x8v __attribute__((ext_vector_type(8)));
typedef float f32x4 __attribute__((ext_vector_type(4)));
typedef float f32x16 __attribute__((ext_vector_type(16)));
typedef u16 u16x8 __attribute__((ext_vector_type(8)));
typedef u16 u16x4 __attribute__((ext_vector_type(4)));

#define AS1C(p) (const __attribute__((address_space(1))) void*)(p)
#define AS3(p)  (__attribute__((address_space(3))) void*)(p)

__device__ __forceinline__ float b2f(u16 u) {
    union { unsigned u; float f; } c; c.u = ((unsigned)u) << 16; return c.f;
}
__device__ __forceinline__ u16 f2b(float f) {
    union { float f; unsigned u; } c; c.f = f;
    unsigned x = c.u + 0x7fffu + ((c.u >> 16) & 1u);   // RNE
    return (u16)(x >> 16);
}

// ------- prep: blocks 0..1023 transpose+cast the 4 weights; 1024..3071 cast x -------
__global__ void prep(const float* __restrict__ x, u16* __restrict__ xb,
                     const float* __restrict__ Wq, const float* __restrict__ Wk,
                     const float* __restrict__ Wv, const float* __restrict__ Wo,
                     u16* __restrict__ wt, u16* __restrict__ wot) {
    if (blockIdx.x < 1024) {
        __shared__ float tl[64][65];
        const int which = blockIdx.x >> 8;
        const float* src = which == 0 ? Wq : which == 1 ? Wk : which == 2 ? Wv : Wo;
        u16* dst = which < 3 ? wt + which * 1048576 : wot;
        const int bx = blockIdx.x & 255;
        const int tx = bx & 15, ty = bx >> 4;
        const int j = threadIdx.x & 63, i0 = threadIdx.x >> 6;
        #pragma unroll
        for (int it = 0; it < 16; ++it) {
            int i = it * 4 + i0;
            tl[i][j] = src[(ty * 64 + i) * 1024 + tx * 64 + j];
        }
        __syncthreads();
        #pragma unroll
        for (int it = 0; it < 16; ++it) {
            int i = it * 4 + i0;
            dst[(tx * 64 + i) * 1024 + ty * 64 + j] = f2b(tl[j][i]);
        }
    } else {
        const long n4 = 8388608L;
        long i = (long)(blockIdx.x - 1024) * blockDim.x + threadIdx.x;
        long stride = 2048L * blockDim.x;
        for (long jj = i; jj < n4; jj += stride) {
            float4 v = ((const float4*)x)[jj];
            u16x4 o = { f2b(v.x), f2b(v.y), f2b(v.z), f2b(v.w) };
            ((u16x4*)xb)[jj] = o;
        }
    }
}

// ================= 256x256-tile NT-GEMM, BK=64, 4-phase single-barrier ======
// r8-proven schedule, fragments switched to 32x32x16 (17% less matrix-pipe
// time per FLOP, half the MFMA instructions; operand mapping HW-verified in r6).
// 512 thr = 8 waves (2M x 4N), wave tile 128x64 = 4mb x 2nb 32x32 tiles.
// LDS 128KB = 2 dbuf x {A 4 units, B 4 units} (unit = 64 rows x 64 k).
// Phase = [ds_reads | 2 stages | (vmcnt) | s_barrier | MFMA x8(32x32)]:
//   P0: (mh0,nh0), stage (T+1).B2,B3   P1: (mh0,nh1), stage (T+1).A1,A3 +vmcnt(8)
//   P2: (mh1,nh0), stage (T+2).A0,A2   P3: (mh1,nh1), stage (T+2).B0,B1 +vmcnt(6)
// Swizzle: 16B slot = kchunk ^ (row&7); rows are 128B so bank = slot only ->
// 16-lane service groups hit 8 distinct slots x2 = conflict-free.
// OUTMODE 1: f32+bias, Bt batched by row-block. OUTMODE 2: bf16 out, fused
// q-softmax (tn<4) and fused exp(k) (tn 4..7).
template<int OUTMODE>
__global__ __launch_bounds__(512, 2) void gemm256(
    const u16* __restrict__ A, const u16* __restrict__ Bt,
    void* __restrict__ Cout, const float* __restrict__ bias,
    const int lda, const int ldc, const int ntn, const int nwg, const long btBatch)
{
    __shared__ __align__(16) u16 lds[65536];   // 128 KB
    const int t = threadIdx.x;
    const int w = t >> 6, lane = t & 63;
    const int l31 = lane & 31, g2 = lane >> 5;
    const int wr = w >> 2, wc = w & 3;

    // XCD-aware bijective swizzle (nwg % 8 == 0)
    const int cpx = nwg >> 3;
    const int bid = blockIdx.x;
    const int swzb = (bid & 7) * cpx + (bid >> 3);
    const int tm = swzb / ntn, tn = swzb - tm * ntn;
    const long row0 = (long)tm << 8, col0 = (long)tn << 8;
    const u16* BtB = Bt + (row0 >> 12) * btBatch;          // batched B (0 = shared)

    // staging: thread t covers row t>>3 of a 64-row unit, 16B slot t&7;
    // slot s holds k-chunk s ^ (row&7) -> pre-swizzled global elem offset eo
    const int eo = (((t & 7) ^ ((t >> 3) & 7)) << 3);
    const u16* pA = A + (row0 + (t >> 3)) * (long)lda + eo;
    const u16* pB = BtB + (col0 + (t >> 3)) * 1024L + eo;
    const long a64 = (long)lda << 6;                    // 64-row stride

#define STG_A(Tt, j) __builtin_amdgcn_global_load_lds(                        \
    AS1C(pA + (long)(j) * a64 + (((Tt) & 15) << 6)),                          \
    AS3(lds + ((((Tt) & 1) << 15) + ((j) << 12) + t * 8)), 16, 0, 0);
#define STG_B(Tt, j) __builtin_amdgcn_global_load_lds(                        \
    AS1C(pB + (long)(j) * 65536L + (((Tt) & 15) << 6)),                       \
    AS3(lds + ((((Tt) & 1) << 15) + 16384 + ((j) << 12) + t * 8)), 16, 0, 0);

    // 32x32 frag reads: A lane row = mb*32 + l31 (unit wr*2+mh, sub i=mb&1),
    // B lane row = nh*32 + l31 (unit wc); kchunk = (ks*2)|g2, slot = kc^(l31&7)
    const int swz = l31 & 7;
    int koff[4];
    #pragma unroll
    for (int ks = 0; ks < 4; ++ks) koff[ks] = ((((ks << 1) | g2) ^ swz) << 3);
    const int aRow = l31 << 6;
    const int bBase = 16384 + (wc << 12) + (l31 << 6);

    u16x8 aM[2][4], b0[4], b1[4];
    f32x16 acc[4][2] = {};

#define RD_A(mh) { _Pragma("unroll") for (int i = 0; i < 2; ++i) {            \
    const int ab = bufE + (((wr << 1) + (mh)) << 12) + ((i) << 11) + aRow;    \
    _Pragma("unroll") for (int ks = 0; ks < 4; ++ks)                          \
        aM[i][ks] = *(const u16x8*)&lds[ab + koff[ks]]; } }
#define RD_B(nh, br) { const int bb = bufE + bBase + ((nh) << 11);            \
    _Pragma("unroll") for (int ks = 0; ks < 4; ++ks)                          \
        br[ks] = *(const u16x8*)&lds[bb + koff[ks]]; }
#define MM(mh, nh, br) { __builtin_amdgcn_s_setprio(1);                       \
    _Pragma("unroll") for (int ks = 0; ks < 4; ++ks)                          \
    { _Pragma("unroll") for (int i = 0; i < 2; ++i)                           \
        acc[(mh) * 2 + i][nh] = __builtin_amdgcn_mfma_f32_32x32x16_bf16(      \
            __builtin_bit_cast(bf16x8v, aM[i][ks]),                           \
            __builtin_bit_cast(bf16x8v, br[ks]),                              \
            acc[(mh) * 2 + i][nh], 0, 0, 0); }                                \
    __builtin_amdgcn_s_setprio(0); }

    // prologue: T0 fully (order A0A2,B0B1,B2B3,A1A3), T1 partial (A0A2,B0B1)
    STG_A(0, 0) STG_A(0, 2) STG_B(0, 0) STG_B(0, 1)
    STG_B(0, 2) STG_B(0, 3) STG_A(0, 1) STG_A(0, 3)
    STG_A(1, 0) STG_A(1, 2) STG_B(1, 0) STG_B(1, 1)
    asm volatile("s_waitcnt vmcnt(6)" ::: "memory");   // T0 first-6 landed
    __builtin_amdgcn_s_barrier();

    #pragma unroll 2
    for (int T = 0; T < 16; ++T) {
        const int bufE = (T & 1) << 15;
        // P0: reads A-mh0 + B-nh0; stage (T+1).B2,B3
        RD_A(0) RD_B(0, b0)
        STG_B(T + 1, 2) STG_B(T + 1, 3)
        __builtin_amdgcn_s_barrier();
        MM(0, 0, b0)
        // P1: reads B-nh1; stage (T+1).A1,A3; vmcnt(8) drains (T).A1,A3
        RD_B(1, b1)
        STG_A(T + 1, 1) STG_A(T + 1, 3)
        asm volatile("s_waitcnt vmcnt(8)" ::: "memory");
        __builtin_amdgcn_s_barrier();
        MM(0, 1, b1)
        // P2: reads A-mh1; stage (T+2).A0,A2
        RD_A(1)
        STG_A(T + 2, 0) STG_A(T + 2, 2)
        __builtin_amdgcn_s_barrier();
        MM(1, 0, b0)
        // P3: stage (T+2).B0,B1; vmcnt(6) drains (T+1)'s first six units
        STG_B(T + 2, 0) STG_B(T + 2, 1)
        asm volatile("s_waitcnt vmcnt(6)" ::: "memory");
        __builtin_amdgcn_s_barrier();
        MM(1, 1, b1)
    }
    asm volatile("s_waitcnt vmcnt(0)" ::: "memory");   // drain wrapped tail stages
#undef STG_A
#undef STG_B
#undef RD_A
#undef RD_B
#undef MM

    // fused q-softmax over head_dim (tn<4: wave's 64 cols = one head).
    // 32x32 C layout: lane holds cols {l31, l31+32}; rows differ by g2 only ->
    // per-row reduce = nb pair + shfl_xor 1..16 (stays within g2 half).
    if (OUTMODE == 2 && tn < 4) {
        #pragma unroll
        for (int mb = 0; mb < 4; ++mb) {
            #pragma unroll
            for (int r = 0; r < 16; ++r) {
                float v0 = acc[mb][0][r], v1 = acc[mb][1][r];
                float m = fmaxf(v0, v1);
                m = fmaxf(m, __shfl_xor(m, 1)); m = fmaxf(m, __shfl_xor(m, 2));
                m = fmaxf(m, __shfl_xor(m, 4)); m = fmaxf(m, __shfl_xor(m, 8));
                m = fmaxf(m, __shfl_xor(m, 16));
                v0 = __expf(v0 - m); v1 = __expf(v1 - m);
                float s = v0 + v1;
                s += __shfl_xor(s, 1); s += __shfl_xor(s, 2); s += __shfl_xor(s, 4);
                s += __shfl_xor(s, 8); s += __shfl_xor(s, 16);
                const float sc = 0.125f / s;             // includes D^-0.5
                acc[mb][0][r] = v0 * sc; acc[mb][1][r] = v1 * sc;
            }
        }
    }
    // fused exp(k) for K region (tn 4..7), f32-accurate
    if (OUTMODE == 2 && tn >= 4 && tn < 8) {
        #pragma unroll
        for (int mb = 0; mb < 4; ++mb)
            #pragma unroll
            for (int nb = 0; nb < 2; ++nb)
                #pragma unroll
                for (int r = 0; r < 16; ++r)
                    acc[mb][nb][r] = __expf(acc[mb][nb][r]);
    }

    // C/D (32x32): col = l31 (+nb*32), row = (r&3) + 8*(r>>2) + 4*g2 (+mb*32)
    const long crow = row0 + wr * 128 + g2 * 4;
    const long ccol = col0 + wc * 64 + l31;
    if (OUTMODE != 1) {
        u16* Cb = (u16*)Cout;
        #pragma unroll
        for (int mb = 0; mb < 4; ++mb) {
            #pragma unroll
            for (int nb = 0; nb < 2; ++nb) {
                #pragma unroll
                for (int r = 0; r < 16; ++r) {
                    long row = crow + mb * 32 + (r & 3) + ((r >> 2) << 3);
                    Cb[row * (long)ldc + ccol + nb * 32] = f2b(acc[mb][nb][r]);
                }
            }
        }
    } else {
        float* Cf = (float*)Cout;
        float bv[2] = { bias[ccol], bias[ccol + 32] };
        #pragma unroll
        for (int mb = 0; mb < 4; ++mb) {
            #pragma unroll
            for (int nb = 0; nb < 2; ++nb) {
                #pragma unroll
                for (int r = 0; r < 16; ++r) {
                    long row = crow + mb * 32 + (r & 3) + ((r >> 2) << 3);
                    Cf[row * (long)ldc + ccol + nb * 32] = acc[mb][nb][r] + bv[nb];
                }
            }
        }
    }
}

// --------- kv[b,h,f,d] = sum_n expk[n,h,f] * v[n,h,d]; colsum side-product ---
// expk precomputed in gemm<2> epilogue; pure load/FMA, f32 LDS pad-68.
__global__ __launch_bounds__(256) void kv_partial(const u16* __restrict__ qkv,
                                                  float* __restrict__ kvp,
                                                  float* __restrict__ psum) {
    __shared__ __align__(16) float kf_s[64 * 68];
    __shared__ __align__(16) float v_s[64 * 68];
    const int t = threadIdx.x;
    const int bx = blockIdx.x;                       // 1024 = 8nc * 16h * 8b
    const int nc = bx & 7, h = (bx >> 3) & 15, b = bx >> 7;
    const int f0 = (t >> 4) << 2;                    // 0..60
    const int d0 = (t & 15) << 2;
    const int lr = t >> 3, lc = (t & 7) << 3;
    const long rowbase = (long)b * 4096 + nc * 512;
    const u16* kfg = qkv + (rowbase + lr) * 3072 + 1024 + h * 64 + lc;
    const u16* vg = kfg + 1024;
    float acc[4][4] = {};
    float cs[4] = {};
    for (int n0 = 0; n0 < 512; n0 += 64) {
        long go = (long)n0 * 3072;
        u16x8 kr0 = *(const u16x8*)(kfg + go);
        u16x8 kr1 = *(const u16x8*)(kfg + go + 32L * 3072);
        u16x8 vr0 = *(const u16x8*)(vg + go);
        u16x8 vr1 = *(const u16x8*)(vg + go + 32L * 3072);
        f32x4 ke0a, ke0b, ke1a, ke1b, vv0a, vv0b, vv1a, vv1b;
        #pragma unroll
        for (int j = 0; j < 4; ++j) {
            ke0a[j] = b2f(kr0[j]);     ke0b[j] = b2f(kr0[j + 4]);
            ke1a[j] = b2f(kr1[j]);     ke1b[j] = b2f(kr1[j + 4]);
            vv0a[j] = b2f(vr0[j]);     vv0b[j] = b2f(vr0[j + 4]);
            vv1a[j] = b2f(vr1[j]);     vv1b[j] = b2f(vr1[j + 4]);
        }
        *(f32x4*)&kf_s[lr * 68 + lc]            = ke0a;
        *(f32x4*)&kf_s[lr * 68 + lc + 4]        = ke0b;
        *(f32x4*)&kf_s[(lr + 32) * 68 + lc]     = ke1a;
        *(f32x4*)&kf_s[(lr + 32) * 68 + lc + 4] = ke1b;
        *(f32x4*)&v_s[lr * 68 + lc]             = vv0a;
        *(f32x4*)&v_s[lr * 68 + lc + 4]         = vv0b;
        *(f32x4*)&v_s[(lr + 32) * 68 + lc]      = vv1a;
        *(f32x4*)&v_s[(lr + 32) * 68 + lc + 4]  = vv1b;
        __syncthreads();
        #pragma unroll 8
        for (int r = 0; r < 64; ++r) {
            f32x4 kf4 = *(const f32x4*)&kf_s[r * 68 + f0];
            f32x4 vf4 = *(const f32x4*)&v_s[r * 68 + d0];
            #pragma unroll
            for (int i = 0; i < 4; ++i) {
                cs[i] += kf4[i];
                #pragma unroll
                for (int jj = 0; jj < 4; ++jj)
                    acc[i][jj] += kf4[i] * vf4[jj];
            }
        }
        __syncthreads();
    }
    float* o = kvp + (long)nc * 524288 + ((long)(b * 16 + h)) * 4096;
    #pragma unroll
    for (int i = 0; i < 4; ++i) {
        #pragma unroll
        for (int jj = 0; jj < 4; ++jj)
            o[(f0 + i) * 64 + d0 + jj] = acc[i][jj];
    }
    if ((t & 15) == 0) {
        float* ps = psum + ((long)nc * 128 + b * 16 + h) * 64 + f0;
        #pragma unroll
        for (int i = 0; i < 4; ++i) ps[i] = cs[i];
    }
}

// --------- combine 8 partials + scale by 1/colsum -> kvN[b,h][f][d] bf16 ---
__global__ void kv_scale(const float* __restrict__ kvp, const float* __restrict__ psum,
                         u16* __restrict__ kvNb) {
    __shared__ float inv_s[64];
    const int bh = blockIdx.x;                       // 128
    const int t = threadIdx.x;
    if (t < 64) {
        float s = 0.f;
        #pragma unroll
        for (int nc = 0; nc < 8; ++nc) s += psum[((long)nc * 128 + bh) * 64 + t];
        inv_s[t] = 1.0f / s;
    }
    __syncthreads();
    const float* p = kvp + (long)bh * 4096;
    u16* o = kvNb + (long)bh * 4096;
    const float inv = inv_s[t >> 2];                 // f = (t*16)/64 = t>>2
    #pragma unroll
    for (int j = 0; j < 4; ++j) {
        const int idx = t * 16 + j * 4;
        f32x4 v = {};
        #pragma unroll
        for (int nc = 0; nc < 8; ++nc) {
            f32x4 pv = *(const f32x4*)&p[(long)nc * 524288 + idx];
            #pragma unroll
            for (int e = 0; e < 4; ++e) v[e] += pv[e];
        }
        u16x4 ov = { f2b(v[0] * inv), f2b(v[1] * inv), f2b(v[2] * inv), f2b(v[3] * inv) };
        *(u16x4*)&o[idx] = ov;
    }
}

// --------- W2T_b[c][h*64+f] = sum_d wot[c][h*64+d] * kvN[b,h][f][d]  (MFMA) ---------
__global__ __launch_bounds__(256) void w2t_mfma(const u16* __restrict__ wot,
                                                const u16* __restrict__ kvNb,
                                                u16* __restrict__ w2t) {
    __shared__ __align__(16) u16 Qs[8192];   // [128][64] bf16, XOR-swizzled chunks
    const int t = threadIdx.x;
    const int bx = blockIdx.x;               // 1024 = 8mt * 16h * 8b
    const int mt = bx & 7, h = (bx >> 3) & 15, b = bx >> 7;
    const int c0 = mt * 128;
    const int wave = t >> 6, lane = t & 63;
    const int wr = wave >> 1, wc = wave & 1;
    const int l16 = lane & 15, g = lane >> 4;

    const int colg = t & 7;
    const int rloc = t >> 3;                 // 0..31
    #pragma unroll
    for (int p = 0; p < 4; ++p) {
        const int row = p * 32 + rloc;       // 0..127
        u16x8 qv = *(const u16x8*)(wot + (long)(c0 + row) * 1024 + h * 64 + colg * 8);
        const int chunk = colg ^ (row & 7);
        *(u16x8*)&Qs[row * 64 + chunk * 8] = qv;
    }
    __syncthreads();

    const u16* kvb = kvNb + ((long)(b * 16 + h) << 12);
    bf16x8v bkv[2][2];
    #pragma unroll
    for (int ni = 0; ni < 2; ++ni) {
        #pragma unroll
        for (int ks = 0; ks < 2; ++ks)
            bkv[ni][ks] = __builtin_bit_cast(bf16x8v,
                *(const u16x8*)(kvb + (wc * 32 + ni * 16 + l16) * 64 + ks * 32 + g * 8));
    }
    bf16x8v aq[4][2];
    #pragma unroll
    for (int mi = 0; mi < 4; ++mi) {
        const int row = wr * 64 + mi * 16 + l16;
        #pragma unroll
        for (int ks = 0; ks < 2; ++ks) {
            const int c16 = (ks * 4 + g) ^ (row & 7);
            aq[mi][ks] = __builtin_bit_cast(bf16x8v,
                *(const u16x8*)&Qs[row * 64 + c16 * 8]);
        }
    }
    f32x4 acc[4][2] = {};
    #pragma unroll
    for (int mi = 0; mi < 4; ++mi) {
        #pragma unroll
        for (int ni = 0; ni < 2; ++ni) {
            acc[mi][ni] = __builtin_amdgcn_mfma_f32_16x16x32_bf16(
                aq[mi][0], bkv[ni][0], acc[mi][ni], 0, 0, 0);
            acc[mi][ni] = __builtin_amdgcn_mfma_f32_16x16x32_bf16(
                aq[mi][1], bkv[ni][1], acc[mi][ni], 0, 0, 0);
        }
    }
    u16* ob = w2t + (long)b * 1048576;
    #pragma unroll
    for (int mi = 0; mi < 4; ++mi) {
        #pragma unroll
        for (int ni = 0; ni < 2; ++ni) {
            int row = c0 + wr * 64 + mi * 16 + g * 4;
            int col = h * 64 + wc * 32 + ni * 16 + l16;
            #pragma unroll
            for (int r = 0; r < 4; ++r)
                ob[(long)(row + r) * 1024 + col] = f2b(acc[mi][ni][r]);
        }
    }
}

extern "C" void kernel_launch(void* const* d_in, const int* in_sizes, int n_in,
                              void* d_out, int out_size, void* d_ws, size_t ws_size,
                              hipStream_t stream) {
    (void)in_sizes; (void)n_in; (void)out_size; (void)ws_size;
    const float* x  = (const float*)d_in[0];
    const float* Wq = (const float*)d_in[1];
    const float* Wk = (const float*)d_in[2];
    const float* Wv = (const float*)d_in[3];
    const float* Wo = (const float*)d_in[4];
    const float* bo = (const float*)d_in[5];

    u16* xb  = (u16*)d_ws;                       // 33,554,432 elems (64 MB)
    u16* wt  = xb + 33554432;                    //  3,145,728
    u16* wot = wt + 3145728;                     //  1,048,576
    u16* qkv = wot + 1048576;                    // 100,663,296
    u16* kvNb = qkv + 100663296;                 //    524,288
    // kvp/psum/w2t alias the xb region (xb dead after gemm<2>; rewritten by
    // prep every call). kvp 16MB + psum 0.25MB + w2t 16MB = 32.3MB < 64MB.
    float* kvp  = (float*)xb;                    //  4,194,304 f32
    float* psum = kvp + 4194304;                 //     65,536 f32
    u16* w2t = (u16*)(psum + 65536);             //  8,388,608 u16 (8 x 1024 x 1024)

    prep<<<3072, 256, 0, stream>>>(x, xb, Wq, Wk, Wv, Wo, wt, wot);
    // QKV = xb @ [Wq|Wk|Wv]^T-laid (M=32768, N=3072, K=1024); softmax+exp fused
    gemm256<2><<<1536, 512, 0, stream>>>(xb, wt, (void*)qkv, nullptr, 1024, 3072, 12, 1536, 0L);
    kv_partial<<<1024, 256, 0, stream>>>(qkv, kvp, psum);
    kv_scale<<<128, 256, 0, stream>>>(kvp, psum, kvNb);
    w2t_mfma<<<1024, 256, 0, stream>>>(wot, kvNb, w2t);
    // out_b = q_sm_b @ W2_b + bo (batched: Bt advances 1M elems per 4096 rows)
    gemm256<1><<<512, 512, 0, stream>>>(qkv, w2t, d_out, bo, 3072, 1024, 4, 512, 1048576L);
}

// Round 13
// 356.056 us; speedup vs baseline: 1.2183x; 1.2183x over previous
//
#include <hip/hip_runtime.h>

// VanillaLinearAttention: B=8 N=4096 C=1024 H=16 D=64, M=B*N=32768.
// prep: cast x + transpose W's; QKV = x@[Wq|Wk|Wv] (256^2 4-phase counted-vmcnt
// 16x16x32 MFMA GEMM, fused q-softmax tn<4 + fused exp(k) tn 4..7);
// kv = expk^T @ v via MFMA (transposed LDS staging, colsum fused);
// kv_scale (1/colsum); W2T_b = wot_h @ kvN_h; out = q_sm @ W2_b + bo (batched).

typedef unsigned short u16;
typedef __bf16 bf16x8v __attribute__((ext_vector_type(8)));
typedef float f32x4 __attribute__((ext_vector_type(4)));
typedef u16 u16x8 __attribute__((ext_vector_type(8)));
typedef u16 u16x4 __attribute__((ext_vector_type(4)));

#define AS1C(p) (const __attribute__((address_space(1))) void*)(p)
#define AS3(p)  (__attribute__((address_space(3))) void*)(p)

__device__ __forceinline__ float b2f(u16 u) {
    union { unsigned u; float f; } c; c.u = ((unsigned)u) << 16; return c.f;
}
__device__ __forceinline__ u16 f2b(float f) {
    union { float f; unsigned u; } c; c.f = f;
    unsigned x = c.u + 0x7fffu + ((c.u >> 16) & 1u);   // RNE
    return (u16)(x >> 16);
}

// ------- prep: blocks 0..1023 transpose+cast the 4 weights; 1024..3071 cast x -------
__global__ void prep(const float* __restrict__ x, u16* __restrict__ xb,
                     const float* __restrict__ Wq, const float* __restrict__ Wk,
                     const float* __restrict__ Wv, const float* __restrict__ Wo,
                     u16* __restrict__ wt, u16* __restrict__ wot) {
    if (blockIdx.x < 1024) {
        __shared__ float tl[64][65];
        const int which = blockIdx.x >> 8;
        const float* src = which == 0 ? Wq : which == 1 ? Wk : which == 2 ? Wv : Wo;
        u16* dst = which < 3 ? wt + which * 1048576 : wot;
        const int bx = blockIdx.x & 255;
        const int tx = bx & 15, ty = bx >> 4;
        const int j = threadIdx.x & 63, i0 = threadIdx.x >> 6;
        #pragma unroll
        for (int it = 0; it < 16; ++it) {
            int i = it * 4 + i0;
            tl[i][j] = src[(ty * 64 + i) * 1024 + tx * 64 + j];
        }
        __syncthreads();
        #pragma unroll
        for (int it = 0; it < 16; ++it) {
            int i = it * 4 + i0;
            dst[(tx * 64 + i) * 1024 + ty * 64 + j] = f2b(tl[j][i]);
        }
    } else {
        const long n4 = 8388608L;
        long i = (long)(blockIdx.x - 1024) * blockDim.x + threadIdx.x;
        long stride = 2048L * blockDim.x;
        for (long jj = i; jj < n4; jj += stride) {
            float4 v = ((const float4*)x)[jj];
            u16x4 o = { f2b(v.x), f2b(v.y), f2b(v.z), f2b(v.w) };
            ((u16x4*)xb)[jj] = o;
        }
    }
}

// ================= 256x256-tile NT-GEMM, BK=64, 4-phase single-barrier ======
// (round-8/11 proven: 207-208us, MfmaUtil 44.5, 0 conflicts, absmax-verified)
// 512 thr = 8 waves (2M x 4N), wave tile 128x64 (8x4 16x16x32 frags).
// LDS 128KB = 2 dbuf x {A 4 units, B 4 units} (unit = 64 rows x 64 k).
// Phase = [ds_reads | 2 stages | (vmcnt) | s_barrier | MFMA x16]:
//   P0: stage (T+1).B2,B3   P1: stage (T+1).A1,A3 + vmcnt(8)
//   P2: stage (T+2).A0,A2   P3: stage (T+2).B0,B1 + vmcnt(6)
// Swizzle: 16B slot = kchunk ^ (row&7), pre-swizzled source + swizzled reads.
// OUTMODE 1: f32+bias, Bt batched by row-block (btBatch elems per 4096 rows).
// OUTMODE 2: bf16 out, fused q-softmax (tn<4) and fused exp(k) (tn 4..7).
template<int OUTMODE>
__global__ __launch_bounds__(512, 2) void gemm256(
    const u16* __restrict__ A, const u16* __restrict__ Bt,
    void* __restrict__ Cout, const float* __restrict__ bias,
    const int lda, const int ldc, const int ntn, const int nwg, const long btBatch)
{
    __shared__ __align__(16) u16 lds[65536];   // 128 KB
    const int t = threadIdx.x;
    const int w = t >> 6, lane = t & 63;
    const int l16 = lane & 15, g = lane >> 4;
    const int wr = w >> 2, wc = w & 3;

    // XCD-aware bijective swizzle (nwg % 8 == 0)
    const int cpx = nwg >> 3;
    const int bid = blockIdx.x;
    const int swzb = (bid & 7) * cpx + (bid >> 3);
    const int tm = swzb / ntn, tn = swzb - tm * ntn;
    const long row0 = (long)tm << 8, col0 = (long)tn << 8;
    const u16* BtB = Bt + (row0 >> 12) * btBatch;          // batched B (0 = shared)

    // staging: thread t covers row t>>3 of a 64-row unit, 16B slot t&7;
    // slot s holds k-chunk s ^ (row&7) -> pre-swizzled global elem offset eo
    const int eo = (((t & 7) ^ ((t >> 3) & 7)) << 3);
    const u16* pA = A + (row0 + (t >> 3)) * (long)lda + eo;
    const u16* pB = BtB + (col0 + (t >> 3)) * 1024L + eo;
    const long a64 = (long)lda << 6;                    // 64-row stride

#define STG_A(Tt, j) __builtin_amdgcn_global_load_lds(                        \
    AS1C(pA + (long)(j) * a64 + (((Tt) & 15) << 6)),                          \
    AS3(lds + ((((Tt) & 1) << 15) + ((j) << 12) + t * 8)), 16, 0, 0);
#define STG_B(Tt, j) __builtin_amdgcn_global_load_lds(                        \
    AS1C(pB + (long)(j) * 65536L + (((Tt) & 15) << 6)),                       \
    AS3(lds + ((((Tt) & 1) << 15) + 16384 + ((j) << 12) + t * 8)), 16, 0, 0);

    // frag reads: row base in 64-elem rows; koff[ks] = ((ks*4+g) ^ (l16&7))*8
    const int swz = l16 & 7;
    const int koff0 = ((0 * 4 + g) ^ swz) << 3;
    const int koff1 = ((1 * 4 + g) ^ swz) << 3;
    const int arow = ((wr << 7) + l16) << 6;            // A row wr*128+l16
    const int brow = 16384 + (((wc << 6) + l16) << 6);  // B row wc*64+l16

    u16x8 aM[4][2], b0[2][2], b1[2][2];
    f32x4 acc[8][4] = {};

#define RD_A(half) { _Pragma("unroll") for (int mi = 0; mi < 4; ++mi) {       \
    const int ab = bufE + arow + ((half) * 64 + mi * 16) * 64;                \
    aM[mi][0] = *(const u16x8*)&lds[ab + koff0];                              \
    aM[mi][1] = *(const u16x8*)&lds[ab + koff1]; } }
#define RD_B(nh, br) { _Pragma("unroll") for (int ni = 0; ni < 2; ++ni) {     \
    const int bb = bufE + brow + ((nh) * 32 + ni * 16) * 64;                  \
    br[ni][0] = *(const u16x8*)&lds[bb + koff0];                              \
    br[ni][1] = *(const u16x8*)&lds[bb + koff1]; } }
#define MM(mh, nh, br) { __builtin_amdgcn_s_setprio(1);                       \
    _Pragma("unroll") for (int mi = 0; mi < 4; ++mi)                          \
    { _Pragma("unroll") for (int ni = 0; ni < 2; ++ni) {                      \
    f32x4 c = acc[(mh)*4 + mi][(nh)*2 + ni];                                  \
    c = __builtin_amdgcn_mfma_f32_16x16x32_bf16(                              \
        __builtin_bit_cast(bf16x8v, aM[mi][0]),                               \
        __builtin_bit_cast(bf16x8v, br[ni][0]), c, 0, 0, 0);                  \
    c = __builtin_amdgcn_mfma_f32_16x16x32_bf16(                              \
        __builtin_bit_cast(bf16x8v, aM[mi][1]),                               \
        __builtin_bit_cast(bf16x8v, br[ni][1]), c, 0, 0, 0);                  \
    acc[(mh)*4 + mi][(nh)*2 + ni] = c; } }                                    \
    __builtin_amdgcn_s_setprio(0); }

    // prologue: T0 fully (order A0A2,B0B1,B2B3,A1A3), T1 partial (A0A2,B0B1)
    STG_A(0, 0) STG_A(0, 2) STG_B(0, 0) STG_B(0, 1)
    STG_B(0, 2) STG_B(0, 3) STG_A(0, 1) STG_A(0, 3)
    STG_A(1, 0) STG_A(1, 2) STG_B(1, 0) STG_B(1, 1)
    asm volatile("s_waitcnt vmcnt(6)" ::: "memory");   // T0 first-6 landed
    __builtin_amdgcn_s_barrier();

    #pragma unroll 2
    for (int T = 0; T < 16; ++T) {
        const int bufE = (T & 1) << 15;
        // P0: reads A-M0 + B-N0; stage (T+1).B2,B3
        RD_A(0) RD_B(0, b0)
        STG_B(T + 1, 2) STG_B(T + 1, 3)
        __builtin_amdgcn_s_barrier();
        MM(0, 0, b0)
        // P1: reads B-N1; stage (T+1).A1,A3; vmcnt(8) drains (T).A1,A3
        RD_B(1, b1)
        STG_A(T + 1, 1) STG_A(T + 1, 3)
        asm volatile("s_waitcnt vmcnt(8)" ::: "memory");
        __builtin_amdgcn_s_barrier();
        MM(0, 1, b1)
        // P2: reads A-M1; stage (T+2).A0,A2
        RD_A(1)
        STG_A(T + 2, 0) STG_A(T + 2, 2)
        __builtin_amdgcn_s_barrier();
        MM(1, 0, b0)
        // P3: stage (T+2).B0,B1; vmcnt(6) drains (T+1)'s first six units
        STG_B(T + 2, 0) STG_B(T + 2, 1)
        asm volatile("s_waitcnt vmcnt(6)" ::: "memory");
        __builtin_amdgcn_s_barrier();
        MM(1, 1, b1)
    }
    asm volatile("s_waitcnt vmcnt(0)" ::: "memory");   // drain wrapped tail stages
#undef STG_A
#undef STG_B
#undef RD_A
#undef RD_B
#undef MM

    // fused q-softmax over head_dim (tn<4: wave's 64 cols = one head)
    if (OUTMODE == 2 && tn < 4) {
        #pragma unroll
        for (int mi = 0; mi < 8; ++mi) {
            #pragma unroll
            for (int r = 0; r < 4; ++r) {
                float v0 = acc[mi][0][r], v1 = acc[mi][1][r];
                float v2 = acc[mi][2][r], v3 = acc[mi][3][r];
                float m = fmaxf(fmaxf(v0, v1), fmaxf(v2, v3));
                m = fmaxf(m, __shfl_xor(m, 1)); m = fmaxf(m, __shfl_xor(m, 2));
                m = fmaxf(m, __shfl_xor(m, 4)); m = fmaxf(m, __shfl_xor(m, 8));
                v0 = __expf(v0 - m); v1 = __expf(v1 - m);
                v2 = __expf(v2 - m); v3 = __expf(v3 - m);
                float s = v0 + v1 + v2 + v3;
                s += __shfl_xor(s, 1); s += __shfl_xor(s, 2);
                s += __shfl_xor(s, 4); s += __shfl_xor(s, 8);
                const float sc = 0.125f / s;             // includes D^-0.5
                acc[mi][0][r] = v0 * sc; acc[mi][1][r] = v1 * sc;
                acc[mi][2][r] = v2 * sc; acc[mi][3][r] = v3 * sc;
            }
        }
    }
    // fused exp(k) for K region (tn 4..7), f32-accurate
    if (OUTMODE == 2 && tn >= 4 && tn < 8) {
        #pragma unroll
        for (int mi = 0; mi < 8; ++mi)
            #pragma unroll
            for (int ni = 0; ni < 4; ++ni)
                #pragma unroll
                for (int r = 0; r < 4; ++r)
                    acc[mi][ni][r] = __expf(acc[mi][ni][r]);
    }

    // C/D: col = lane&15, row = (lane>>4)*4 + reg
    const long crow = row0 + wr * 128 + g * 4;
    const long ccol = col0 + wc * 64 + l16;
    if (OUTMODE != 1) {
        u16* Cb = (u16*)Cout;
        #pragma unroll
        for (int mi = 0; mi < 8; ++mi) {
            #pragma unroll
            for (int ni = 0; ni < 4; ++ni) {
                long base = (crow + mi * 16) * (long)ldc + ccol + ni * 16;
                #pragma unroll
                for (int r = 0; r < 4; ++r)
                    Cb[base + (long)r * ldc] = f2b(acc[mi][ni][r]);
            }
        }
    } else {
        float* Cf = (float*)Cout;
        float bv[4];
        #pragma unroll
        for (int ni = 0; ni < 4; ++ni) bv[ni] = bias[ccol + ni * 16];
        #pragma unroll
        for (int mi = 0; mi < 8; ++mi) {
            #pragma unroll
            for (int ni = 0; ni < 4; ++ni) {
                long base = (crow + mi * 16) * (long)ldc + ccol + ni * 16;
                #pragma unroll
                for (int r = 0; r < 4; ++r)
                    Cf[base + (long)r * ldc] = acc[mi][ni][r] + bv[ni];
            }
        }
    }
}

// ===== kv via MFMA: kv[b,h][f][d] = sum_n expk[n,h,f]*v[n,h,d]; colsum fused =====
// Per block (b,h,nc): 512 n-rows in 8 tiles of 64. Stage expk,v TRANSPOSED into
// LDS [64 f|d][72 n] with n-block swizzle n' = n ^ (((row>>3)&7)<<3):
// write banks = 4c + r/2 (all distinct); b128 reads 16B-aligned, 2-way max.
// MFMA: wave w owns f-rows w*16..+15; per tile 2 k-steps x 4 d-blocks = 8 MFMA.
__global__ __launch_bounds__(256) void kv_mfma(const u16* __restrict__ qkv,
                                               float* __restrict__ kvp,
                                               float* __restrict__ psum) {
    __shared__ __align__(16) u16 eT[64 * 72];
    __shared__ __align__(16) u16 vT[64 * 72];
    __shared__ float csb[256 * 8];
    const int t = threadIdx.x;
    const int bx = blockIdx.x;                 // 1024 = 8nc * 16h * 8b
    const int nc = bx & 7, h = (bx >> 3) & 15, b = bx >> 7;
    const int r = t >> 3;                      // 0..31 (n within half-tile)
    const int c = t & 7;                       // col group
    const long rowbase = (long)b * 4096 + nc * 512;
    const u16* eg = qkv + (rowbase + r) * 3072 + 1024 + h * 64 + c * 8;
    const u16* vg = eg + 1024;
    const int w = t >> 6, lane = t & 63;
    const int l16 = lane & 15, g = lane >> 4;

    float cs[8] = {};
    f32x4 acc[4] = {};

    // read-side addresses (constant across tiles): A row f = w*16+l16, B row d
    int aoff[2], boff[4][2];
    #pragma unroll
    for (int ks = 0; ks < 2; ++ks) {
        const int f = w * 16 + l16;
        aoff[ks] = f * 72 + ((ks * 32 + g * 8) ^ (((f >> 3) & 7) << 3));
        #pragma unroll
        for (int db = 0; db < 4; ++db) {
            const int d = db * 16 + l16;
            boff[db][ks] = d * 72 + ((ks * 32 + g * 8) ^ (((d >> 3) & 7) << 3));
        }
    }

    for (int n0 = 0; n0 < 512; n0 += 64) {
        const long go = (long)n0 * 3072;
        u16x8 e0 = *(const u16x8*)(eg + go);
        u16x8 e1 = *(const u16x8*)(eg + go + 32L * 3072);
        u16x8 v0 = *(const u16x8*)(vg + go);
        u16x8 v1 = *(const u16x8*)(vg + go + 32L * 3072);
        #pragma unroll
        for (int j = 0; j < 8; ++j) {
            cs[j] += b2f(e0[j]) + b2f(e1[j]);
            const int f = c * 8 + j;
            const int sw = ((f >> 3) & 7) << 3;        // = c<<3
            eT[f * 72 + (r ^ sw)]        = e0[j];
            eT[f * 72 + ((r + 32) ^ sw)] = e1[j];
            vT[f * 72 + (r ^ sw)]        = v0[j];
            vT[f * 72 + ((r + 32) ^ sw)] = v1[j];
        }
        __syncthreads();
        #pragma unroll
        for (int ks = 0; ks < 2; ++ks) {
            bf16x8v af = __builtin_bit_cast(bf16x8v, *(const u16x8*)&eT[aoff[ks]]);
            #pragma unroll
            for (int db = 0; db < 4; ++db) {
                bf16x8v bf = __builtin_bit_cast(bf16x8v, *(const u16x8*)&vT[boff[db][ks]]);
                acc[db] = __builtin_amdgcn_mfma_f32_16x16x32_bf16(af, bf, acc[db], 0, 0, 0);
            }
        }
        __syncthreads();
    }

    // write kv partial: C row = f = w*16 + g*4 + rr, col = d = db*16 + l16
    float* o = kvp + (long)nc * 524288 + ((long)(b * 16 + h)) * 4096;
    #pragma unroll
    for (int db = 0; db < 4; ++db) {
        #pragma unroll
        for (int rr = 0; rr < 4; ++rr)
            o[(w * 16 + g * 4 + rr) * 64 + db * 16 + l16] = acc[db][rr];
    }

    // colsum reduce (deterministic): csb[t][j]; thread f<64 sums its column
    #pragma unroll
    for (int j = 0; j < 8; ++j) csb[t * 8 + j] = cs[j];
    __syncthreads();
    if (t < 64) {
        const int cc = t >> 3, jj = t & 7;
        float s = 0.f;
        #pragma unroll 8
        for (int rr = 0; rr < 32; ++rr) s += csb[(cc + 8 * rr) * 8 + jj];
        psum[((long)nc * 128 + b * 16 + h) * 64 + t] = s;
    }
}

// --------- combine 8 partials + scale by 1/colsum -> kvN[b,h][f][d] bf16 ---
__global__ void kv_scale(const float* __restrict__ kvp, const float* __restrict__ psum,
                         u16* __restrict__ kvNb) {
    __shared__ float inv_s[64];
    const int bh = blockIdx.x;                       // 128
    const int t = threadIdx.x;
    if (t < 64) {
        float s = 0.f;
        #pragma unroll
        for (int nc = 0; nc < 8; ++nc) s += psum[((long)nc * 128 + bh) * 64 + t];
        inv_s[t] = 1.0f / s;
    }
    __syncthreads();
    const float* p = kvp + (long)bh * 4096;
    u16* o = kvNb + (long)bh * 4096;
    const float inv = inv_s[t >> 2];                 // f = (t*16)/64 = t>>2
    #pragma unroll
    for (int j = 0; j < 4; ++j) {
        const int idx = t * 16 + j * 4;
        f32x4 v = {};
        #pragma unroll
        for (int nc = 0; nc < 8; ++nc) {
            f32x4 pv = *(const f32x4*)&p[(long)nc * 524288 + idx];
            #pragma unroll
            for (int e = 0; e < 4; ++e) v[e] += pv[e];
        }
        u16x4 ov = { f2b(v[0] * inv), f2b(v[1] * inv), f2b(v[2] * inv), f2b(v[3] * inv) };
        *(u16x4*)&o[idx] = ov;
    }
}

// --------- W2T_b[c][h*64+f] = sum_d wot[c][h*64+d] * kvN[b,h][f][d]  (MFMA) ---------
__global__ __launch_bounds__(256) void w2t_mfma(const u16* __restrict__ wot,
                                                const u16* __restrict__ kvNb,
                                                u16* __restrict__ w2t) {
    __shared__ __align__(16) u16 Qs[8192];   // [128][64] bf16, XOR-swizzled chunks
    const int t = threadIdx.x;
    const int bx = blockIdx.x;               // 1024 = 8mt * 16h * 8b
    const int mt = bx & 7, h = (bx >> 3) & 15, b = bx >> 7;
    const int c0 = mt * 128;
    const int wave = t >> 6, lane = t & 63;
    const int wr = wave >> 1, wc = wave & 1;
    const int l16 = lane & 15, g = lane >> 4;

    const int colg = t & 7;
    const int rloc = t >> 3;                 // 0..31
    #pragma unroll
    for (int p = 0; p < 4; ++p) {
        const int row = p * 32 + rloc;       // 0..127
        u16x8 qv = *(const u16x8*)(wot + (long)(c0 + row) * 1024 + h * 64 + colg * 8);
        const int chunk = colg ^ (row & 7);
        *(u16x8*)&Qs[row * 64 + chunk * 8] = qv;
    }
    __syncthreads();

    const u16* kvb = kvNb + ((long)(b * 16 + h) << 12);
    bf16x8v bkv[2][2];
    #pragma unroll
    for (int ni = 0; ni < 2; ++ni) {
        #pragma unroll
        for (int ks = 0; ks < 2; ++ks)
            bkv[ni][ks] = __builtin_bit_cast(bf16x8v,
                *(const u16x8*)(kvb + (wc * 32 + ni * 16 + l16) * 64 + ks * 32 + g * 8));
    }
    bf16x8v aq[4][2];
    #pragma unroll
    for (int mi = 0; mi < 4; ++mi) {
        const int row = wr * 64 + mi * 16 + l16;
        #pragma unroll
        for (int ks = 0; ks < 2; ++ks) {
            const int c16 = (ks * 4 + g) ^ (row & 7);
            aq[mi][ks] = __builtin_bit_cast(bf16x8v,
                *(const u16x8*)&Qs[row * 64 + c16 * 8]);
        }
    }
    f32x4 acc[4][2] = {};
    #pragma unroll
    for (int mi = 0; mi < 4; ++mi) {
        #pragma unroll
        for (int ni = 0; ni < 2; ++ni) {
            acc[mi][ni] = __builtin_amdgcn_mfma_f32_16x16x32_bf16(
                aq[mi][0], bkv[ni][0], acc[mi][ni], 0, 0, 0);
            acc[mi][ni] = __builtin_amdgcn_mfma_f32_16x16x32_bf16(
                aq[mi][1], bkv[ni][1], acc[mi][ni], 0, 0, 0);
        }
    }
    u16* ob = w2t + (long)b * 1048576;
    #pragma unroll
    for (int mi = 0; mi < 4; ++mi) {
        #pragma unroll
        for (int ni = 0; ni < 2; ++ni) {
            int row = c0 + wr * 64 + mi * 16 + g * 4;
            int col = h * 64 + wc * 32 + ni * 16 + l16;
            #pragma unroll
            for (int r = 0; r < 4; ++r)
                ob[(long)(row + r) * 1024 + col] = f2b(acc[mi][ni][r]);
        }
    }
}

extern "C" void kernel_launch(void* const* d_in, const int* in_sizes, int n_in,
                              void* d_out, int out_size, void* d_ws, size_t ws_size,
                              hipStream_t stream) {
    (void)in_sizes; (void)n_in; (void)out_size; (void)ws_size;
    const float* x  = (const float*)d_in[0];
    const float* Wq = (const float*)d_in[1];
    const float* Wk = (const float*)d_in[2];
    const float* Wv = (const float*)d_in[3];
    const float* Wo = (const float*)d_in[4];
    const float* bo = (const float*)d_in[5];

    u16* xb  = (u16*)d_ws;                       // 33,554,432 elems (64 MB)
    u16* wt  = xb + 33554432;                    //  3,145,728
    u16* wot = wt + 3145728;                     //  1,048,576
    u16* qkv = wot + 1048576;                    // 100,663,296
    u16* kvNb = qkv + 100663296;                 //    524,288
    // kvp/psum/w2t alias the xb region (xb dead after gemm<2>; rewritten by
    // prep every call). kvp 16MB + psum 0.25MB + w2t 16MB = 32.3MB < 64MB.
    float* kvp  = (float*)xb;                    //  4,194,304 f32
    float* psum = kvp + 4194304;                 //     65,536 f32
    u16* w2t = (u16*)(psum + 65536);             //  8,388,608 u16 (8 x 1024 x 1024)

    prep<<<3072, 256, 0, stream>>>(x, xb, Wq, Wk, Wv, Wo, wt, wot);
    // QKV = xb @ [Wq|Wk|Wv]^T-laid (M=32768, N=3072, K=1024); softmax+exp fused
    gemm256<2><<<1536, 512, 0, stream>>>(xb, wt, (void*)qkv, nullptr, 1024, 3072, 12, 1536, 0L);
    kv_mfma<<<1024, 256, 0, stream>>>(qkv, kvp, psum);
    kv_scale<<<128, 256, 0, stream>>>(kvp, psum, kvNb);
    w2t_mfma<<<1024, 256, 0, stream>>>(wot, kvNb, w2t);
    // out_b = q_sm_b @ W2_b + bo (batched: Bt advances 1M elems per 4096 rows)
    gemm256<1><<<512, 512, 0, stream>>>(qkv, w2t, d_out, bo, 3072, 1024, 4, 512, 1048576L);
}